// Round 8
// baseline (237.059 us; speedup 1.0000x reference)
//
#include <hip/hip_runtime.h>
#include <hip/hip_bf16.h>

#define N_PTS 12288
#define DIM   64
#define KSEL  16
#define EPS_F 1e-5f
#define TMARGIN 2.0f   // covers 2x bf16 cross-pair screen noise (proven r1-r7)

typedef __bf16 bf16x8 __attribute__((ext_vector_type(8)));
typedef float  f32x16 __attribute__((ext_vector_type(16)));

// Hand-rolled grid barrier (proven r7; ~40us cheaper than cooperative launch).
// Safe: grid=256, 1 block/CU, co-resident by construction. bar memset to 0.
__device__ __forceinline__ void grid_sync(int* bar)
{
    __syncthreads();
    if (threadIdx.x == 0) {
        __hip_atomic_fetch_add(bar, 1, __ATOMIC_RELEASE, __HIP_MEMORY_SCOPE_AGENT);
        while (__hip_atomic_load(bar, __ATOMIC_ACQUIRE, __HIP_MEMORY_SCOPE_AGENT)
               < (int)gridDim.x)
            __builtin_amdgcn_s_sleep(2);
    }
    __syncthreads();
}

template<int CVN>
__device__ __forceinline__ void rank_core(const unsigned* __restrict__ drow,
                                          int S, int l32, int* __restrict__ fj)
{
    unsigned cv[CVN]; int rk[CVN];
    #pragma unroll
    for (int t = 0; t < CVN; ++t) {
        cv[t] = (t * 32 + l32 < S) ? drow[t * 32 + l32] : 0xFFFFFFFFu;
        rk[t] = 0;
    }
    #pragma unroll 4
    for (int m = 0; m < S; ++m) {
        const unsigned o = drow[m];
        #pragma unroll
        for (int t = 0; t < CVN; ++t) rk[t] += (o < cv[t]) ? 1 : 0;
    }
    #pragma unroll
    for (int t = 0; t < CVN; ++t)
        if (rk[t] < 32 && cv[t] != 0xFFFFFFFFu)
            fj[rk[t]] = (int)(cv[t] & 0x3FFFu);
}

// ---------------------------------------------------------------------------
// Single kernel, grid 256 = 1 block/CU, 512 thr = 8 waves; block owns 48 i x
// ALL j; wave owns a 1536-j slice in 48 steps of 32 j.
// Screen: mfma_f32_32x32x16_bf16, A = j-fragment (rows=j), B = i-fragment
// (cols=i) -> each lane holds 16 j-candidates for ONE i (one threshold).
// K=96 via 5 MFMAs: 4 coord + 1 ext (k 64..79; 80..95 all-zero, skipped).
//   A_ext(j) = [sj_hi, sj_lo, 1, 1, 0..]   B_ext(i) = [-.5, -.5, -bh, -bl, 0..]
//   => acc = dot - sj/2 - (sq_i+eps)/2 = -d2/2;  pass iff acc > -T/2.
//  P1: quarter-sample (12 steps), branchless per-lane top-2 -> pool 32/row;
//      T[row] = 17th smallest + TMARGIN (17th absorbs the diagonal).
//  P2: full 48 steps; per lane per tile: 15-fmax tree + ONE cmp gate; hits
//      push (pack|j) into per-row dense list via LDS atomic (cap 256 = 6.4sig).
//  P3: rank-select top-32 + fp64 refine + rank-16 laplacian (proven r4-r7).
// ---------------------------------------------------------------------------
__global__ __launch_bounds__(512) void mega_kernel(
    const float* __restrict__ coords,
    const float* __restrict__ pot,
    float* __restrict__ s1,
    float* __restrict__ sx,
    int* __restrict__ bar,
    __hip_bfloat16* __restrict__ chi,
    __hip_bfloat16* __restrict__ chiX,
    float* __restrict__ out)
{
    constexpr int ROWS = 48, DCAP = 256, DPAD = 257;
    constexpr int JSL  = N_PTS / 8;              // 1536
    constexpr int STEPS = JSL / 32;              // 48

    __shared__ float    colsh[8][64];
    __shared__ float    sqs8[8];
    __shared__ float    sqloc[ROWS];
    __shared__ float    pool[ROWS][32];
    __shared__ float    TrowS[ROWS];
    __shared__ unsigned dense[ROWS * DPAD];      // 49.3 KB
    __shared__ int      cnt[ROWS];
    __shared__ int      finj[16][32];
    __shared__ double   refd[16][32];
    __shared__ double   s_inv_den;

    const int tid  = threadIdx.x;
    const int lane = tid & 63;
    const int wave = tid >> 6;                   // 0..7
    const int l31  = lane & 31;
    const int half = lane >> 5;                  // 0/1
    const int ibase = (int)blockIdx.x * ROWS;

    // ---------------- phase A: stats + bf16 copies for own 48 rows ---------
    float colsum = 0.f, sqsum = 0.f;
    #pragma unroll 1
    for (int k = 0; k < 6; ++k) {
        const int rl = wave * 6 + k, gr = ibase + rl;
        const float x = coords[gr * DIM + lane];
        chi[gr * DIM + lane] = __float2bfloat16(x);
        colsum += x;
        float p = x * x;
        #pragma unroll
        for (int off = 32; off > 0; off >>= 1) p += __shfl_xor(p, off, 64);
        if (lane == 0) { sqloc[rl] = p; sqsum += p; }
        if (lane < 16) {                         // ext row: 16 bf16 (k 64..79)
            __hip_bfloat16 v = __float2bfloat16(0.0f);
            if (lane == 0)      v = __float2bfloat16(p);
            else if (lane == 1) {
                const float h = (float)__float2bfloat16(p);
                v = __float2bfloat16(p - h);
            }
            else if (lane < 4)  v = __float2bfloat16(1.0f);
            chiX[gr * 16 + lane] = v;
        }
    }
    colsh[wave][lane] = colsum;
    if (lane == 0) sqs8[wave] = sqsum;
    if (tid < ROWS) cnt[tid] = 0;
    __syncthreads();
    if (wave == 0) {
        float c = 0.f;
        #pragma unroll
        for (int w8 = 0; w8 < 8; ++w8) c += colsh[w8][lane];
        atomicAdd(&sx[lane], c);
    }
    if (tid == 0) {
        float t = 0.f;
        #pragma unroll
        for (int w8 = 0; w8 < 8; ++w8) t += sqs8[w8];
        atomicAdd(s1, t);
    }
    grid_sync(bar);                              // chi/chiX + s1/sx final

    if (tid == 0) {
        double S1 = (double)s1[0], m2 = 0.0;
        for (int d = 0; d < DIM; ++d) { double t = (double)sx[d]; m2 += t * t; }
        const double NN = (double)N_PTS;
        s_inv_den = 1.0 / ((2.0 * NN * S1 - 2.0 * m2) / (NN * NN)
                           + 1e-5 + 1e6 / NN + 1e-5);
    }

    // ---------------- B-fragments: 2 i-tiles x 5 K-groups ------------------
    const bf16x8* cp  = (const bf16x8*)chi;
    const bf16x8* cpX = (const bf16x8*)chiX;
    bf16x8 zf;
    #pragma unroll
    for (int e = 0; e < 8; ++e) zf[e] = (__bf16)0.0f;

    bf16x8 Bf[2][5];
    const int  i0r = ibase + l31;                // tile0: cols = i 0..31
    const bool t1v = (l31 < 16);                 // tile1: cols 0..15 = i 32..47
    const int  i1r = ibase + 32 + (l31 & 15);
    #pragma unroll
    for (int m = 0; m < 4; ++m) {
        Bf[0][m] = cp[i0r * 8 + 2 * m + half];
        Bf[1][m] = t1v ? cp[i1r * 8 + 2 * m + half] : zf;
    }
    {
        bf16x8 v = zf;
        if (half == 0) {
            const float bs = sqloc[l31] + EPS_F;
            const __bf16 bh = (__bf16)(0.5f * bs);
            const __bf16 bl = (__bf16)(0.5f * bs - (float)bh);
            v[0] = (__bf16)(-0.5f); v[1] = (__bf16)(-0.5f);
            v[2] = (__bf16)(-(float)bh); v[3] = (__bf16)(-(float)bl);
        }
        Bf[0][4] = v;
        v = zf;
        if (half == 0 && t1v) {
            const float bs = sqloc[32 + l31] + EPS_F;
            const __bf16 bh = (__bf16)(0.5f * bs);
            const __bf16 bl = (__bf16)(0.5f * bs - (float)bh);
            v[0] = (__bf16)(-0.5f); v[1] = (__bf16)(-0.5f);
            v[2] = (__bf16)(-(float)bh); v[3] = (__bf16)(-(float)bl);
        }
        Bf[1][4] = v;
    }

    const int jw = wave * JSL;
    const f32x16 Z = {0.f,0.f,0.f,0.f,0.f,0.f,0.f,0.f,
                      0.f,0.f,0.f,0.f,0.f,0.f,0.f,0.f};

    auto LDA = [&](int s, bf16x8 (&A)[5]) {
        const int jr = jw + s * 32 + l31;
        A[0] = cp[jr * 8 + half];
        A[1] = cp[jr * 8 + 2 + half];
        A[2] = cp[jr * 8 + 4 + half];
        A[3] = cp[jr * 8 + 6 + half];
        A[4] = cpX[jr * 2 + half];
    };
    auto ACC2 = [&](const bf16x8 (&A)[5], f32x16& a0, f32x16& a1) {
        a0 = __builtin_amdgcn_mfma_f32_32x32x16_bf16(A[0], Bf[0][0], Z, 0, 0, 0);
        a1 = __builtin_amdgcn_mfma_f32_32x32x16_bf16(A[0], Bf[1][0], Z, 0, 0, 0);
        #pragma unroll
        for (int m = 1; m < 5; ++m) {
            a0 = __builtin_amdgcn_mfma_f32_32x32x16_bf16(A[m], Bf[0][m], a0, 0, 0, 0);
            a1 = __builtin_amdgcn_mfma_f32_32x32x16_bf16(A[m], Bf[1][m], a1, 0, 0, 0);
        }
    };

    // ---------------- P1: quarter-sample top-2 (of acc = -d2/2) ------------
    float p00 = -1e30f, p01 = -1e30f, p10 = -1e30f, p11 = -1e30f;
    auto TOP2 = [&](const f32x16& a, float& m0, float& m1) {
        #pragma unroll
        for (int r = 0; r < 16; ++r) {
            const float v = a[r];
            const bool g = v > m0;
            m1 = g ? m0 : fmaxf(m1, v);
            m0 = fmaxf(m0, v);
        }
    };
    {
        bf16x8 Aa[5], Ab[5];
        LDA(0, Aa); LDA(4, Ab);
        #pragma unroll 1
        for (int k = 0; k < 12; k += 2) {
            { f32x16 a0, a1; ACC2(Aa, a0, a1);
              int sn = (k + 2) * 4; LDA(sn < STEPS ? sn : 0, Aa);
              TOP2(a0, p00, p01); TOP2(a1, p10, p11); }
            { f32x16 a0, a1; ACC2(Ab, a0, a1);
              int sn = (k + 3) * 4; LDA(sn < STEPS ? sn : 0, Ab);
              TOP2(a0, p00, p01); TOP2(a1, p10, p11); }
        }
    }
    {
        const int slot = wave * 4 + half * 2;
        pool[l31][slot]     = -2.f * p00;
        pool[l31][slot + 1] = -2.f * p01;
        if (t1v) {
            pool[32 + l31][slot]     = -2.f * p10;
            pool[32 + l31][slot + 1] = -2.f * p11;
        }
    }
    __syncthreads();

    // T = 17th smallest of 32 pooled d2 (+margin); 16 half-waves x 3 passes
    const int hw  = tid >> 5;                    // 0..15
    const int l32 = tid & 31;
    #pragma unroll 1
    for (int pass = 0; pass < 3; ++pass) {
        const int row = pass * 16 + hw;
        const float val = pool[row][l32];
        int rank = 0;
        #pragma unroll 8
        for (int m = 0; m < 32; ++m) {
            const float o = pool[row][m];
            rank += (o < val || (o == val && m < l32)) ? 1 : 0;
        }
        if (rank == 16) TrowS[row] = val + TMARGIN;
    }
    __syncthreads();

    const float tthr0 = -0.5f * TrowS[l31];      // pass iff acc > -T/2
    const float tthr1 = t1v ? -0.5f * TrowS[32 + l31] : 1e30f;

    // ---------------- P2: full screen ----------------
    auto EPI = [&](int s, const f32x16& a, float tthr, int lrow) {
        float mx = fmaxf(fmaxf(fmaxf(a[0], a[1]), fmaxf(a[2], a[3])),
                         fmaxf(fmaxf(a[4], a[5]), fmaxf(a[6], a[7])));
        mx = fmaxf(mx, fmaxf(fmaxf(fmaxf(a[8], a[9]),  fmaxf(a[10], a[11])),
                             fmaxf(fmaxf(a[12], a[13]), fmaxf(a[14], a[15]))));
        if (mx > tthr) {
            const int jb = jw + s * 32 + 4 * half;
            #pragma unroll
            for (int r = 0; r < 16; ++r) {
                if (a[r] > tthr) {
                    const float d2 = -2.f * a[r];
                    const unsigned pk = (__float_as_uint(d2) & 0xFFFFC000u)
                                      | (unsigned)(jb + (r & 3) + 8 * (r >> 2));
                    const int idx = atomicAdd(&cnt[lrow], 1);
                    if (idx < DCAP) dense[lrow * DPAD + idx] = pk;
                }
            }
        }
    };
    {
        bf16x8 Aa[5], Ab[5];
        LDA(0, Aa); LDA(1, Ab);
        #pragma unroll 1
        for (int s = 0; s < STEPS; s += 2) {
            { f32x16 a0, a1; ACC2(Aa, a0, a1);
              int sn = s + 2; LDA(sn < STEPS ? sn : 0, Aa);
              EPI(s, a0, tthr0, l31); EPI(s, a1, tthr1, 32 + (l31 & 15)); }
            { f32x16 a0, a1; ACC2(Ab, a0, a1);
              int sn = s + 3; LDA(sn < STEPS ? sn : 0, Ab);
              EPI(s + 1, a0, tthr0, l31); EPI(s + 1, a1, tthr1, 32 + (l31 & 15)); }
        }
    }
    __syncthreads();

    // ---------------- P3: merge (16 rows per pass, 3 passes) ---------------
    const double inv_den = s_inv_den;
    #pragma unroll 1
    for (int pass = 0; pass < 3; ++pass) {
        const int row  = pass * 16 + hw;
        const int grow = ibase + row;
        int S = cnt[row]; S = S < DCAP ? S : DCAP;
        finj[hw][l32] = grow;                    // default: self -> inert slot

        const unsigned* drow = dense + row * DPAD;
        if (S <= 96) rank_core<3>(drow, S, l32, finj[hw]);
        else         rank_core<8>(drow, S, l32, finj[hw]);
        __syncthreads();

        // fp64 refine (dot + both norms) + rank-16 + laplacian
        const int j = finj[hw][l32];
        const float4* xi = (const float4*)(coords + grow * DIM);
        const float4* xj = (const float4*)(coords + j * DIM);
        double dot = 0.0, sqi = 0.0, sqj = 0.0;
        #pragma unroll
        for (int q = 0; q < DIM / 4; ++q) {
            const float4 a = xi[q], b = xj[q];
            dot += (double)a.x * (double)b.x + (double)a.y * (double)b.y
                 + (double)a.z * (double)b.z + (double)a.w * (double)b.w;
            sqi += (double)a.x * (double)a.x + (double)a.y * (double)a.y
                 + (double)a.z * (double)a.z + (double)a.w * (double)a.w;
            sqj += (double)b.x * (double)b.x + (double)b.y * (double)b.y
                 + (double)b.z * (double)b.z + (double)b.w * (double)b.w;
        }
        double d2 = sqi + sqj + 1e-5 - 2.0 * dot;
        if (j == grow) d2 = 1e300;               // self / pad slots
        refd[hw][l32] = d2;
        __syncthreads();

        int rank = 0;
        #pragma unroll 1
        for (int m = 0; m < 32; ++m) {
            const double o = refd[hw][m];
            rank += (o < d2 || (o == d2 && m < l32)) ? 1 : 0;
        }
        const double wgt = exp(-d2 * inv_den);
        double contrib = (rank < KSEL && j != grow)
                       ? wgt * ((double)pot[j] - (double)pot[grow]) : 0.0;
        #pragma unroll
        for (int off = 1; off < 32; off <<= 1)
            contrib += __shfl_xor(contrib, off, 64);
        if (l32 == 0) out[grow] = (float)contrib;
        __syncthreads();                         // finj/refd reused next pass
    }
}

extern "C" void kernel_launch(void* const* d_in, const int* in_sizes, int n_in,
                              void* d_out, int out_size, void* d_ws, size_t ws_size,
                              hipStream_t stream)
{
    (void)in_sizes; (void)n_in; (void)out_size; (void)ws_size;
    const float* coords = (const float*)d_in[0];
    const float* pot    = (const float*)d_in[1];
    // d_in[2] is k (always 16, compiled in as KSEL)

    char* w = (char*)d_ws;
    float* s1 = (float*)w;                                   // [1]
    float* sx = (float*)(w + 4);                             // [DIM]
    int*   bar = (int*)(w + 512);                            // [1]
    __hip_bfloat16* chi  = (__hip_bfloat16*)(w + 1024);      // [N*64] 1.57 MB
    __hip_bfloat16* chiX = (__hip_bfloat16*)(w + 1024 + (size_t)N_PTS * DIM * 2);
                                                             // [N*16] 393 KB

    hipMemsetAsync((void*)w, 0, 1024, stream);               // s1+sx+bar
    mega_kernel<<<dim3(N_PTS / 48), dim3(512), 0, stream>>>(
        coords, pot, s1, sx, bar, chi, chiX, (float*)d_out);
}

// Round 9
// 234.249 us; speedup vs baseline: 1.0120x; 1.0120x over previous
//
#include <hip/hip_runtime.h>
#include <hip/hip_bf16.h>

#define N_PTS 12288
#define DIM   64
#define KSEL  16
#define EPS_F 1e-5f
#define TMARGIN 2.0f   // covers 2x bf16 cross-pair screen noise (proven r1-r8)

typedef __bf16 bf16x8 __attribute__((ext_vector_type(8)));
typedef float  f32x16 __attribute__((ext_vector_type(16)));

// Hand-rolled grid barrier (proven r7/r8). Safe: grid=256, 1 block/CU.
__device__ __forceinline__ void grid_sync(int* bar)
{
    __syncthreads();
    if (threadIdx.x == 0) {
        __hip_atomic_fetch_add(bar, 1, __ATOMIC_RELEASE, __HIP_MEMORY_SCOPE_AGENT);
        while (__hip_atomic_load(bar, __ATOMIC_ACQUIRE, __HIP_MEMORY_SCOPE_AGENT)
               < (int)gridDim.x)
            __builtin_amdgcn_s_sleep(2);
    }
    __syncthreads();
}

template<int CVN>
__device__ __forceinline__ void rank_core(const unsigned* __restrict__ drow,
                                          int S, int l32, int* __restrict__ fj)
{
    unsigned cv[CVN]; int rk[CVN];
    #pragma unroll
    for (int t = 0; t < CVN; ++t) {
        cv[t] = (t * 32 + l32 < S) ? drow[t * 32 + l32] : 0xFFFFFFFFu;
        rk[t] = 0;
    }
    #pragma unroll 4
    for (int m = 0; m < S; ++m) {
        const unsigned o = drow[m];
        #pragma unroll
        for (int t = 0; t < CVN; ++t) rk[t] += (o < cv[t]) ? 1 : 0;
    }
    #pragma unroll
    for (int t = 0; t < CVN; ++t)
        if (rk[t] < 32 && cv[t] != 0xFFFFFFFFu)
            fj[rk[t]] = (int)(cv[t] & 0x3FFFu);
}

// ---------------------------------------------------------------------------
// Single kernel, grid 256 = 1 block/CU, 512 thr = 8 waves; block owns 48 i x
// ALL j; wave owns a 1536-j slice in 48 steps of 32 j.
// Screen: mfma_f32_32x32x16_bf16, A = j-fragment, B = i-fragment; lane holds
// 16 j-candidates for ONE i (one threshold). K=96 via 5 MFMAs (4 coord + ext).
//   acc = dot - sj/2 - (sq_i+eps)/2 = -d2/2; pass iff acc > -T/2.
// Survivor key = (as_uint(acc) & 0xFFFFC000) | j : for all-negative accs,
// uint order == ascending d2 (diagonal may go positive -> sorts first ->
// killed in merge). No atomics in the hot path (r8's regression): survivors
// go to PRIVATE per-lane LDS columns (CAPP=12, lambda~6.9) with a per-row
// shared overflow (OCAP=96, cold; structural max 16*12+96 = DCAP, no drops).
//  P1: quarter-sample top-2 -> 32-pool/row; T = 17th pooled d2 + TMARGIN.
//  P2: full screen, per-element test + private push.
//  P2b: prefix compaction (16 segs/row) -> dense rows.
//  P3: rank-select top-32 + fp64 refine + rank-16 laplacian (proven r4-r8).
// ---------------------------------------------------------------------------
__global__ __launch_bounds__(512) void mega_kernel(
    const float* __restrict__ coords,
    const float* __restrict__ pot,
    float* __restrict__ s1,
    float* __restrict__ sx,
    int* __restrict__ bar,
    __hip_bfloat16* __restrict__ chi,
    __hip_bfloat16* __restrict__ chiX,
    float* __restrict__ out)
{
    constexpr int ROWS = 48, CAPP = 12, OCAP = 96;
    constexpr int DCAP = 16 * CAPP + OCAP;       // 288 structural max/row
    constexpr int DPAD = DCAP + 1;               // 289
    constexpr int JSL  = N_PTS / 8;              // 1536
    constexpr int STEPS = JSL / 32;              // 48

    __shared__ float    colsh[8][64];
    __shared__ float    sqs8[8];
    __shared__ float    sqloc[ROWS];
    __shared__ float    pool[ROWS][32];
    __shared__ float    TrowS[ROWS];
    __shared__ unsigned buf[2 * CAPP * 512];     // 49152 B private columns
    __shared__ int      cntT[2][16][32];         // [tile][seg][col]
    __shared__ unsigned dense[ROWS * DPAD];      // 55488 B
    __shared__ unsigned ovf[ROWS][OCAP];         // 18432 B
    __shared__ int      ovcnt[ROWS];
    __shared__ int      stotS[ROWS];
    __shared__ int      finj[16][32];
    __shared__ double   refd[16][32];
    __shared__ double   s_inv_den;

    const int tid  = threadIdx.x;
    const int lane = tid & 63;
    const int wave = tid >> 6;                   // 0..7
    const int l31  = lane & 31;
    const int half = lane >> 5;                  // 0/1
    const int ibase = (int)blockIdx.x * ROWS;

    // ---------------- phase A: stats + bf16 copies for own 48 rows ---------
    float colsum = 0.f, sqsum = 0.f;
    #pragma unroll 1
    for (int k = 0; k < 6; ++k) {
        const int rl = wave * 6 + k, gr = ibase + rl;
        const float x = coords[gr * DIM + lane];
        chi[gr * DIM + lane] = __float2bfloat16(x);
        colsum += x;
        float p = x * x;
        #pragma unroll
        for (int off = 32; off > 0; off >>= 1) p += __shfl_xor(p, off, 64);
        if (lane == 0) { sqloc[rl] = p; sqsum += p; }
        if (lane < 16) {                         // ext row: 16 bf16 (k 64..79)
            __hip_bfloat16 v = __float2bfloat16(0.0f);
            if (lane == 0)      v = __float2bfloat16(p);
            else if (lane == 1) {
                const float h = (float)__float2bfloat16(p);
                v = __float2bfloat16(p - h);
            }
            else if (lane < 4)  v = __float2bfloat16(1.0f);
            chiX[gr * 16 + lane] = v;
        }
    }
    colsh[wave][lane] = colsum;
    if (lane == 0) sqs8[wave] = sqsum;
    if (tid < ROWS) ovcnt[tid] = 0;
    __syncthreads();
    if (wave == 0) {
        float c = 0.f;
        #pragma unroll
        for (int w8 = 0; w8 < 8; ++w8) c += colsh[w8][lane];
        atomicAdd(&sx[lane], c);
    }
    if (tid == 0) {
        float t = 0.f;
        #pragma unroll
        for (int w8 = 0; w8 < 8; ++w8) t += sqs8[w8];
        atomicAdd(s1, t);
    }
    grid_sync(bar);                              // chi/chiX + s1/sx final

    if (tid == 0) {
        double S1 = (double)s1[0], m2 = 0.0;
        for (int d = 0; d < DIM; ++d) { double t = (double)sx[d]; m2 += t * t; }
        const double NN = (double)N_PTS;
        s_inv_den = 1.0 / ((2.0 * NN * S1 - 2.0 * m2) / (NN * NN)
                           + 1e-5 + 1e6 / NN + 1e-5);
    }

    // ---------------- B-fragments: 2 i-tiles x 5 K-groups ------------------
    const bf16x8* cp  = (const bf16x8*)chi;
    const bf16x8* cpX = (const bf16x8*)chiX;
    bf16x8 zf;
    #pragma unroll
    for (int e = 0; e < 8; ++e) zf[e] = (__bf16)0.0f;

    bf16x8 Bf[2][5];
    const int  i0r = ibase + l31;                // tile0: cols = i 0..31
    const bool t1v = (l31 < 16);                 // tile1: cols 0..15 = i 32..47
    const int  i1r = ibase + 32 + (l31 & 15);
    #pragma unroll
    for (int m = 0; m < 4; ++m) {
        Bf[0][m] = cp[i0r * 8 + 2 * m + half];
        Bf[1][m] = t1v ? cp[i1r * 8 + 2 * m + half] : zf;
    }
    {
        bf16x8 v = zf;
        if (half == 0) {
            const float bs = sqloc[l31] + EPS_F;
            const __bf16 bh = (__bf16)(0.5f * bs);
            const __bf16 bl = (__bf16)(0.5f * bs - (float)bh);
            v[0] = (__bf16)(-0.5f); v[1] = (__bf16)(-0.5f);
            v[2] = (__bf16)(-(float)bh); v[3] = (__bf16)(-(float)bl);
        }
        Bf[0][4] = v;
        v = zf;
        if (half == 0 && t1v) {
            const float bs = sqloc[32 + l31] + EPS_F;
            const __bf16 bh = (__bf16)(0.5f * bs);
            const __bf16 bl = (__bf16)(0.5f * bs - (float)bh);
            v[0] = (__bf16)(-0.5f); v[1] = (__bf16)(-0.5f);
            v[2] = (__bf16)(-(float)bh); v[3] = (__bf16)(-(float)bl);
        }
        Bf[1][4] = v;
    }

    const int jw = wave * JSL;
    const f32x16 Z = {0.f,0.f,0.f,0.f,0.f,0.f,0.f,0.f,
                      0.f,0.f,0.f,0.f,0.f,0.f,0.f,0.f};

    auto LDA = [&](int s, bf16x8 (&A)[5]) {
        const int jr = jw + s * 32 + l31;
        A[0] = cp[jr * 8 + half];
        A[1] = cp[jr * 8 + 2 + half];
        A[2] = cp[jr * 8 + 4 + half];
        A[3] = cp[jr * 8 + 6 + half];
        A[4] = cpX[jr * 2 + half];
    };
    auto ACC2 = [&](const bf16x8 (&A)[5], f32x16& a0, f32x16& a1) {
        a0 = __builtin_amdgcn_mfma_f32_32x32x16_bf16(A[0], Bf[0][0], Z, 0, 0, 0);
        a1 = __builtin_amdgcn_mfma_f32_32x32x16_bf16(A[0], Bf[1][0], Z, 0, 0, 0);
        #pragma unroll
        for (int m = 1; m < 5; ++m) {
            a0 = __builtin_amdgcn_mfma_f32_32x32x16_bf16(A[m], Bf[0][m], a0, 0, 0, 0);
            a1 = __builtin_amdgcn_mfma_f32_32x32x16_bf16(A[m], Bf[1][m], a1, 0, 0, 0);
        }
    };

    // ---------------- P1: quarter-sample top-2 (of acc = -d2/2) ------------
    float p00 = -1e30f, p01 = -1e30f, p10 = -1e30f, p11 = -1e30f;
    auto TOP2 = [&](const f32x16& a, float& m0, float& m1) {
        #pragma unroll
        for (int r = 0; r < 16; ++r) {
            const float v = a[r];
            const bool g = v > m0;
            m1 = g ? m0 : fmaxf(m1, v);
            m0 = fmaxf(m0, v);
        }
    };
    {
        bf16x8 Aa[5], Ab[5];
        LDA(0, Aa); LDA(4, Ab);
        #pragma unroll 1
        for (int k = 0; k < 12; k += 2) {
            { f32x16 a0, a1; ACC2(Aa, a0, a1);
              int sn = (k + 2) * 4; LDA(sn < STEPS ? sn : 0, Aa);
              TOP2(a0, p00, p01); TOP2(a1, p10, p11); }
            { f32x16 a0, a1; ACC2(Ab, a0, a1);
              int sn = (k + 3) * 4; LDA(sn < STEPS ? sn : 0, Ab);
              TOP2(a0, p00, p01); TOP2(a1, p10, p11); }
        }
    }
    {
        const int slot = wave * 4 + half * 2;
        pool[l31][slot]     = -2.f * p00;
        pool[l31][slot + 1] = -2.f * p01;
        if (t1v) {
            pool[32 + l31][slot]     = -2.f * p10;
            pool[32 + l31][slot + 1] = -2.f * p11;
        }
    }
    __syncthreads();

    // T = 17th smallest of 32 pooled d2 (+margin); 16 half-waves x 3 passes
    const int hw  = tid >> 5;                    // 0..15
    const int l32 = tid & 31;
    #pragma unroll 1
    for (int pass = 0; pass < 3; ++pass) {
        const int row = pass * 16 + hw;
        const float val = pool[row][l32];
        int rank = 0;
        #pragma unroll 8
        for (int m = 0; m < 32; ++m) {
            const float o = pool[row][m];
            rank += (o < val || (o == val && m < l32)) ? 1 : 0;
        }
        if (rank == 16) TrowS[row] = val + TMARGIN;
    }
    __syncthreads();

    const float tthr0 = -0.5f * TrowS[l31];      // pass iff acc > -T/2
    const float tthr1 = t1v ? -0.5f * TrowS[32 + l31] : 1e30f;
    const int   row1  = 32 + (l31 & 15);

    // ---------------- P2: full screen, atomic-free pushes ------------------
    int ct0 = 0, ct1 = 0;
    auto EPI = [&](int s, const f32x16& a0, const f32x16& a1) {
        const int jb = jw + s * 32 + 4 * half;
        #pragma unroll
        for (int r = 0; r < 16; ++r) {
            const unsigned joff = (unsigned)(jb + (r & 3) + 8 * (r >> 2));
            if (a0[r] > tthr0) {
                const unsigned pk = (__float_as_uint(a0[r]) & 0xFFFFC000u) | joff;
                if (ct0 < CAPP) { buf[ct0 * 512 + tid] = pk; ++ct0; }
                else { const int sl = atomicAdd(&ovcnt[l31], 1);
                       if (sl < OCAP) ovf[l31][sl] = pk; }
            }
            if (a1[r] > tthr1) {
                const unsigned pk = (__float_as_uint(a1[r]) & 0xFFFFC000u) | joff;
                if (ct1 < CAPP) { buf[(CAPP + ct1) * 512 + tid] = pk; ++ct1; }
                else { const int sl = atomicAdd(&ovcnt[row1], 1);
                       if (sl < OCAP) ovf[row1][sl] = pk; }
            }
        }
    };
    {
        bf16x8 Aa[5], Ab[5];
        LDA(0, Aa); LDA(1, Ab);
        #pragma unroll 1
        for (int s = 0; s < STEPS; s += 2) {
            { f32x16 a0, a1; ACC2(Aa, a0, a1);
              int sn = s + 2; LDA(sn < STEPS ? sn : 0, Aa);
              EPI(s, a0, a1); }
            { f32x16 a0, a1; ACC2(Ab, a0, a1);
              int sn = s + 3; LDA(sn < STEPS ? sn : 0, Ab);
              EPI(s + 1, a0, a1); }
        }
    }
    const int seg = wave * 2 + half;             // 0..15
    cntT[0][seg][l31] = ct0;
    if (t1v) cntT[1][seg][l31] = ct1;
    __syncthreads();

    // ---------------- P2b: prefix compaction (16 segs per row) -------------
    {
        int b0 = 0, b1 = 0;
        #pragma unroll 4
        for (int sg = 0; sg < 16; ++sg) {
            if (sg < seg) {
                b0 += cntT[0][sg][l31];
                b1 += cntT[1][sg][l31 & 15];
            }
        }
        for (int p = 0; p < ct0; ++p)
            dense[l31 * DPAD + b0 + p] = buf[p * 512 + tid];
        if (t1v)
            for (int p = 0; p < ct1; ++p)
                dense[row1 * DPAD + b1 + p] = buf[(CAPP + p) * 512 + tid];
    }
    __syncthreads();
    if (wave == 0 && tid < ROWS) {               // finalize 48 rows
        const int row = tid;
        int tot = 0;
        if (row < 32) {
            #pragma unroll 4
            for (int sg = 0; sg < 16; ++sg) tot += cntT[0][sg][row];
        } else {
            #pragma unroll 4
            for (int sg = 0; sg < 16; ++sg) tot += cntT[1][sg][row - 32];
        }
        const int ov = ovcnt[row] < OCAP ? ovcnt[row] : OCAP;
        for (int o = 0; o < ov; ++o) dense[row * DPAD + tot + o] = ovf[row][o];
        stotS[row] = tot + ov;
    }
    __syncthreads();

    // ---------------- P3: merge (16 rows per pass, 3 passes) ---------------
    const double inv_den = s_inv_den;
    #pragma unroll 1
    for (int pass = 0; pass < 3; ++pass) {
        const int row  = pass * 16 + hw;
        const int grow = ibase + row;
        const int S    = stotS[row];
        finj[hw][l32] = grow;                    // default: self -> inert slot

        const unsigned* drow = dense + row * DPAD;
        if (S <= 96) rank_core<3>(drow, S, l32, finj[hw]);
        else         rank_core<9>(drow, S, l32, finj[hw]);
        __syncthreads();

        // fp64 refine (dot + both norms) + rank-16 + laplacian
        const int j = finj[hw][l32];
        const float4* xi = (const float4*)(coords + grow * DIM);
        const float4* xj = (const float4*)(coords + j * DIM);
        double dot = 0.0, sqi = 0.0, sqj = 0.0;
        #pragma unroll
        for (int q = 0; q < DIM / 4; ++q) {
            const float4 a = xi[q], b = xj[q];
            dot += (double)a.x * (double)b.x + (double)a.y * (double)b.y
                 + (double)a.z * (double)b.z + (double)a.w * (double)b.w;
            sqi += (double)a.x * (double)a.x + (double)a.y * (double)a.y
                 + (double)a.z * (double)a.z + (double)a.w * (double)a.w;
            sqj += (double)b.x * (double)b.x + (double)b.y * (double)b.y
                 + (double)b.z * (double)b.z + (double)b.w * (double)b.w;
        }
        double d2 = sqi + sqj + 1e-5 - 2.0 * dot;
        if (j == grow) d2 = 1e300;               // self / pad slots
        refd[hw][l32] = d2;
        __syncthreads();

        int rank = 0;
        #pragma unroll 1
        for (int m = 0; m < 32; ++m) {
            const double o = refd[hw][m];
            rank += (o < d2 || (o == d2 && m < l32)) ? 1 : 0;
        }
        const double wgt = exp(-d2 * inv_den);
        double contrib = (rank < KSEL && j != grow)
                       ? wgt * ((double)pot[j] - (double)pot[grow]) : 0.0;
        #pragma unroll
        for (int off = 1; off < 32; off <<= 1)
            contrib += __shfl_xor(contrib, off, 64);
        if (l32 == 0) out[grow] = (float)contrib;
        __syncthreads();                         // finj/refd reused next pass
    }
}

extern "C" void kernel_launch(void* const* d_in, const int* in_sizes, int n_in,
                              void* d_out, int out_size, void* d_ws, size_t ws_size,
                              hipStream_t stream)
{
    (void)in_sizes; (void)n_in; (void)out_size; (void)ws_size;
    const float* coords = (const float*)d_in[0];
    const float* pot    = (const float*)d_in[1];
    // d_in[2] is k (always 16, compiled in as KSEL)

    char* w = (char*)d_ws;
    float* s1 = (float*)w;                                   // [1]
    float* sx = (float*)(w + 4);                             // [DIM]
    int*   bar = (int*)(w + 512);                            // [1]
    __hip_bfloat16* chi  = (__hip_bfloat16*)(w + 1024);      // [N*64] 1.57 MB
    __hip_bfloat16* chiX = (__hip_bfloat16*)(w + 1024 + (size_t)N_PTS * DIM * 2);
                                                             // [N*16] 393 KB

    hipMemsetAsync((void*)w, 0, 1024, stream);               // s1+sx+bar
    mega_kernel<<<dim3(N_PTS / 48), dim3(512), 0, stream>>>(
        coords, pot, s1, sx, bar, chi, chiX, (float*)d_out);
}

// Round 10
// 225.293 us; speedup vs baseline: 1.0522x; 1.0398x over previous
//
#include <hip/hip_runtime.h>
#include <hip/hip_bf16.h>

#define N_PTS 12288
#define DIM   64
#define KSEL  16
#define EPS_F 1e-5f
#define TMARGIN 2.0f   // covers 2x bf16 cross-pair screen noise (proven r1-r9)

typedef __bf16 bf16x8 __attribute__((ext_vector_type(8)));
typedef float  f32x4  __attribute__((ext_vector_type(4)));

// Hand-rolled grid barrier (proven r7-r9). Safe: grid=256, 1 block/CU.
__device__ __forceinline__ void grid_sync(int* bar)
{
    __syncthreads();
    if (threadIdx.x == 0) {
        __hip_atomic_fetch_add(bar, 1, __ATOMIC_RELEASE, __HIP_MEMORY_SCOPE_AGENT);
        while (__hip_atomic_load(bar, __ATOMIC_ACQUIRE, __HIP_MEMORY_SCOPE_AGENT)
               < (int)gridDim.x)
            __builtin_amdgcn_s_sleep(2);
    }
    __syncthreads();
}

template<int CVN>
__device__ __forceinline__ void rank_core(const unsigned* __restrict__ drow,
                                          int S, int l32, int* __restrict__ fj)
{
    unsigned cv[CVN]; int rk[CVN];
    #pragma unroll
    for (int t = 0; t < CVN; ++t) {
        cv[t] = (t * 32 + l32 < S) ? drow[t * 32 + l32] : 0xFFFFFFFFu;
        rk[t] = 0;
    }
    #pragma unroll 4
    for (int m = 0; m < S; ++m) {
        const unsigned o = drow[m];
        #pragma unroll
        for (int t = 0; t < CVN; ++t) rk[t] += (o < cv[t]) ? 1 : 0;
    }
    #pragma unroll
    for (int t = 0; t < CVN; ++t)
        if (rk[t] < 32 && cv[t] != 0xFFFFFFFFu)
            fj[rk[t]] = (int)(cv[t] & 0x3FFFu);
}

// ---------------------------------------------------------------------------
// r7 geometry (best measured): grid 256 = 1 block/CU, 512 thr = 8 waves;
// block owns 48 i (3 x 16-col B-tiles) x ALL j; wave owns a 1536-j slice in
// 96 steps of 16 j. mfma_f32_16x16x32_bf16, K=96 via 3 MFMAs (norms folded:
// acc = -d2/2; one cmp per candidate; A-loads fully sector-dense).
// Diffs vs r7: P1 quarter-sample (24 steps); P2 EPI software-pipelined one
// step behind its MFMA (X/Y acc states); survivor keys packed from raw acc
// bits (uint asc == d2 asc for acc<0; acc>0 = near-zero d2, refined exactly);
// caps CAPP=10/OCAP=32 for the looser quarter-sample threshold.
// ---------------------------------------------------------------------------
__global__ __launch_bounds__(512) void mega_kernel(
    const float* __restrict__ coords,
    const float* __restrict__ pot,
    float* __restrict__ s1,
    float* __restrict__ sx,
    int* __restrict__ bar,
    __hip_bfloat16* __restrict__ chi,
    __hip_bfloat16* __restrict__ chiX,
    float* __restrict__ out)
{
    constexpr int ROWS = 48, TIL = 3, CAPP = 10, OCAP = 32;
    constexpr int SEGS = 32;                     // 8 waves x 4 quads
    constexpr int DCAP = SEGS * CAPP + OCAP;     // 352 structural max/row
    constexpr int DPAD = DCAP + 1;               // 353
    constexpr int JSL  = N_PTS / 8;              // 1536
    constexpr int STEPS = JSL / 16;              // 96

    __shared__ float    colsh[8][64];
    __shared__ float    sqs8[8];
    __shared__ float    sqloc[ROWS];
    __shared__ float    TrowS[ROWS];
    __shared__ unsigned buf[TIL * CAPP * 512];   // 61440 B
    __shared__ int      cntT[TIL][8][4][16];
    __shared__ __align__(16) unsigned dense[ROWS * DPAD];  // 67776 B
    __shared__ unsigned ovf[ROWS][OCAP];
    __shared__ int      ovcnt[ROWS];
    __shared__ int      stotS[ROWS];
    __shared__ int      finj[16][32];
    __shared__ double   refd[16][32];
    __shared__ double   s_inv_den;

    // P1 pool aliased onto dense: pool is dead before the first dense write
    // (P2b compaction), and 48*64*4 = 12288 B <= sizeof(dense).
    float (*pool)[64] = (float (*)[64])dense;

    const int tid  = threadIdx.x;
    const int lane = tid & 63;
    const int wave = tid >> 6;                   // 0..7
    const int col  = lane & 15;
    const int quad = lane >> 4;
    const int ibase = (int)blockIdx.x * ROWS;

    // ---------------- phase A: stats + bf16 copies for own 48 rows ---------
    float colsum = 0.f, sqsum = 0.f;
    #pragma unroll 1
    for (int k = 0; k < 6; ++k) {
        const int rl = wave * 6 + k, gr = ibase + rl;
        const float x = coords[gr * DIM + lane];
        chi[gr * DIM + lane] = __float2bfloat16(x);
        colsum += x;
        float p = x * x;
        #pragma unroll
        for (int off = 32; off > 0; off >>= 1) p += __shfl_xor(p, off, 64);
        if (lane == 0) { sqloc[rl] = p; sqsum += p; }
        if (lane < 8) {                          // ext row: 8 bf16 (k 64..71)
            const __hip_bfloat16 h = __float2bfloat16(p);
            const float lo = p - (float)h;
            __hip_bfloat16 v;
            if (lane == 0)      v = h;
            else if (lane == 1) v = __float2bfloat16(lo);
            else if (lane < 4)  v = __float2bfloat16(1.0f);
            else                v = __float2bfloat16(0.0f);
            chiX[gr * 8 + lane] = v;
        }
    }
    colsh[wave][lane] = colsum;
    if (lane == 0) sqs8[wave] = sqsum;
    if (tid < ROWS) ovcnt[tid] = 0;
    __syncthreads();
    if (wave == 0) {
        float c = 0.f;
        #pragma unroll
        for (int w8 = 0; w8 < 8; ++w8) c += colsh[w8][lane];
        atomicAdd(&sx[lane], c);
    }
    if (tid == 0) {
        float t = 0.f;
        #pragma unroll
        for (int w8 = 0; w8 < 8; ++w8) t += sqs8[w8];
        atomicAdd(s1, t);
    }
    grid_sync(bar);                              // chi/chiX + s1/sx final

    if (tid == 0) {
        double S1 = (double)s1[0], m2 = 0.0;
        for (int d = 0; d < DIM; ++d) { double t = (double)sx[d]; m2 += t * t; }
        const double NN = (double)N_PTS;
        s_inv_den = 1.0 / ((2.0 * NN * S1 - 2.0 * m2) / (NN * NN)
                           + 1e-5 + 1e6 / NN + 1e-5);
    }

    // ---------------- B-fragments (3 tiles x {lo, hi, ext}) ----------------
    const bf16x8* cp  = (const bf16x8*)chi;
    const bf16x8* cpX = (const bf16x8*)chiX;
    bf16x8 bA[TIL], bB[TIL], b2[TIL];
    #pragma unroll
    for (int t = 0; t < TIL; ++t) {
        const int it = ibase + t * 16 + col;
        bA[t] = cp[it * 8 + quad];
        bB[t] = cp[it * 8 + quad + 4];
        bf16x8 v;
        #pragma unroll
        for (int e = 0; e < 8; ++e) v[e] = (__bf16)0.0f;
        if (quad == 0) {                         // ext dims 0..3 live in quad 0
            const float bs = sqloc[t * 16 + col] + EPS_F;
            const __bf16 bh = (__bf16)(0.5f * bs);
            const __bf16 bl = (__bf16)(0.5f * bs - (float)bh);
            v[0] = (__bf16)(-0.5f); v[1] = (__bf16)(-0.5f);
            v[2] = (__bf16)(-(float)bh); v[3] = (__bf16)(-(float)bl);
        }
        b2[t] = v;
    }

    const int jw  = wave * JSL;
    const int seg = wave * 4 + quad;             // 0..31

    auto LD = [&](int s, bf16x8& A0, bf16x8& A1, bf16x8& A2) {
        const int ar = jw + s * 16 + col;
        A0 = cp[ar * 8 + quad];
        A1 = cp[ar * 8 + quad + 4];
        A2 = cpX[ar];                            // quads 1-3 killed by b2 zeros
    };
    auto MFMA3 = [&](const bf16x8& A0, const bf16x8& A1, const bf16x8& A2,
                     f32x4 (&acc)[TIL]) {
        #pragma unroll
        for (int t = 0; t < TIL; ++t) {
            f32x4 a = {0.f, 0.f, 0.f, 0.f};
            a = __builtin_amdgcn_mfma_f32_16x16x32_bf16(A0, bA[t], a, 0, 0, 0);
            a = __builtin_amdgcn_mfma_f32_16x16x32_bf16(A1, bB[t], a, 0, 0, 0);
            a = __builtin_amdgcn_mfma_f32_16x16x32_bf16(A2, b2[t], a, 0, 0, 0);
            acc[t] = a;                          // acc = -d2/2
        }
    };

    // ---------------- P1: quarter-sample top-2 (steps 0,4,...,92) ----------
    float m0[TIL], m1[TIL];
    #pragma unroll
    for (int t = 0; t < TIL; ++t) { m0[t] = -1e30f; m1[t] = -1e30f; }
    {
        bf16x8 A0[4], A1[4], A2[4];
        #pragma unroll
        for (int p = 0; p < 4; ++p) LD(4 * p, A0[p], A1[p], A2[p]);
        #pragma unroll 1
        for (int k = 0; k < 24; k += 4) {
            #pragma unroll
            for (int p = 0; p < 4; ++p) {
                f32x4 acc[TIL];
                MFMA3(A0[p], A1[p], A2[p], acc);
                int sn = 4 * (k + p + 4);
                sn = (sn < STEPS) ? sn : 0;      // harmless reload at the tail
                LD(sn, A0[p], A1[p], A2[p]);
                #pragma unroll
                for (int t = 0; t < TIL; ++t) {
                    #pragma unroll
                    for (int r = 0; r < 4; ++r) {
                        const float da = acc[t][r];
                        const bool g = da > m0[t];
                        m1[t] = g ? m0[t] : fmaxf(m1[t], da);
                        m0[t] = fmaxf(m0[t], da);
                    }
                }
            }
        }
    }
    #pragma unroll
    for (int t = 0; t < TIL; ++t) {              // two smallest d2 per bucket
        pool[t * 16 + col][seg * 2]     = -2.f * m0[t];
        pool[t * 16 + col][seg * 2 + 1] = -2.f * m1[t];
    }
    __syncthreads();

    // T = 17th smallest of 64 pooled d2 (+margin); wave -> rows 6w..6w+5
    #pragma unroll 1
    for (int rr = 0; rr < 6; ++rr) {
        const int row = wave * 6 + rr;
        const float val = pool[row][lane];
        int rank = 0;
        #pragma unroll 8
        for (int m = 0; m < 64; ++m) {
            const float o = pool[row][m];
            rank += (o < val || (o == val && m < lane)) ? 1 : 0;
        }
        if (rank == 16) TrowS[row] = val + TMARGIN;
    }
    __syncthreads();                             // pool dead from here (alias)

    float tthr[TIL];
    #pragma unroll
    for (int t = 0; t < TIL; ++t) tthr[t] = -0.5f * TrowS[t * 16 + col];

    // ---------------- P2: full screen, EPI pipelined one step back ---------
    int ct[TIL] = {0, 0, 0};
    auto EPI = [&](int s, const f32x4 (&acc)[TIL]) {
        const int jq = jw + s * 16 + quad * 4;
        #pragma unroll
        for (int t = 0; t < TIL; ++t) {
            const float mx = fmaxf(fmaxf(acc[t][0], acc[t][1]),
                                   fmaxf(acc[t][2], acc[t][3]));
            if (mx > tthr[t]) {
                if (__all(ct[t] <= CAPP - 4)) {
                    // branchless dense push: write@ct, ct += hit.
                    #pragma unroll
                    for (int r = 0; r < 4; ++r) {
                        const unsigned pk =
                            (__float_as_uint(acc[t][r]) & 0xFFFFC000u)
                            | (unsigned)(jq + r);
                        buf[(t * CAPP + ct[t]) * 512 + tid] = pk;
                        ct[t] += (acc[t][r] > tthr[t]) ? 1 : 0;
                    }
                } else {                         // near-full: careful + ovf
                    #pragma unroll
                    for (int r = 0; r < 4; ++r) {
                        if (acc[t][r] > tthr[t]) {
                            const unsigned pk =
                                (__float_as_uint(acc[t][r]) & 0xFFFFC000u)
                                | (unsigned)(jq + r);
                            if (ct[t] < CAPP) {
                                buf[(t * CAPP + ct[t]) * 512 + tid] = pk;
                                ++ct[t];
                            } else {
                                const int row = t * 16 + col;
                                const int sl = atomicAdd(&ovcnt[row], 1);
                                if (sl < OCAP) ovf[row][sl] = pk;
                            }
                        }
                    }
                }
            }
        }
    };
    {
        bf16x8 A0[4], A1[4], A2[4];
        #pragma unroll
        for (int p = 0; p < 4; ++p) LD(p, A0[p], A1[p], A2[p]);
        f32x4 X[TIL], Y[TIL];
        MFMA3(A0[0], A1[0], A2[0], X);           // step 0
        LD(4, A0[0], A1[0], A2[0]);
        #pragma unroll 1
        for (int s = 0; s < STEPS - 4; s += 4) {
            MFMA3(A0[1], A1[1], A2[1], Y);       // step s+1
            { int sn = s + 5; sn = sn < STEPS ? sn : 0; LD(sn, A0[1], A1[1], A2[1]); }
            EPI(s, X);
            MFMA3(A0[2], A1[2], A2[2], X);       // step s+2
            { int sn = s + 6; sn = sn < STEPS ? sn : 0; LD(sn, A0[2], A1[2], A2[2]); }
            EPI(s + 1, Y);
            MFMA3(A0[3], A1[3], A2[3], Y);       // step s+3
            { int sn = s + 7; sn = sn < STEPS ? sn : 0; LD(sn, A0[3], A1[3], A2[3]); }
            EPI(s + 2, X);
            MFMA3(A0[0], A1[0], A2[0], X);       // step s+4
            { int sn = s + 8; sn = sn < STEPS ? sn : 0; LD(sn, A0[0], A1[0], A2[0]); }
            EPI(s + 3, Y);
        }
        // tail: MFMA steps 93..95, EPI 92..95 (X currently holds step 92)
        MFMA3(A0[1], A1[1], A2[1], Y); EPI(STEPS - 4, X);
        MFMA3(A0[2], A1[2], A2[2], X); EPI(STEPS - 3, Y);
        MFMA3(A0[3], A1[3], A2[3], Y); EPI(STEPS - 2, X);
        EPI(STEPS - 1, Y);
    }
    cntT[0][wave][quad][col] = ct[0];
    cntT[1][wave][quad][col] = ct[1];
    cntT[2][wave][quad][col] = ct[2];
    __syncthreads();

    // ---------------- compaction (prefix over 32 segment counts) -----------
    {
        int bs[TIL] = {0, 0, 0}, tot[TIL] = {0, 0, 0};
        #pragma unroll 4
        for (int sg = 0; sg < SEGS; ++sg) {
            #pragma unroll
            for (int t = 0; t < TIL; ++t) {
                const int c = cntT[t][sg >> 2][sg & 3][col];
                if (sg < seg) bs[t] += c;
                tot[t] += c;
            }
        }
        #pragma unroll
        for (int t = 0; t < TIL; ++t)
            for (int p = 0; p < ct[t]; ++p)
                dense[(t * 16 + col) * DPAD + bs[t] + p] = buf[(t * CAPP + p) * 512 + tid];
        if (wave == 0 && quad == 0) {            // 16 lanes finalize 48 rows
            #pragma unroll
            for (int t = 0; t < TIL; ++t) {
                const int row = t * 16 + col;
                const int ov = ovcnt[row] < OCAP ? ovcnt[row] : OCAP;
                for (int o = 0; o < ov; ++o) dense[row * DPAD + tot[t] + o] = ovf[row][o];
                stotS[row] = tot[t] + ov;
            }
        }
    }
    __syncthreads();

    // ---------------- P3: merge (16 rows per pass, 3 passes) ---------------
    const double inv_den = s_inv_den;
    const int hw  = tid >> 5;                    // 0..15
    const int l32 = tid & 31;
    #pragma unroll 1
    for (int pass = 0; pass < 3; ++pass) {
        const int row  = pass * 16 + hw;
        const int grow = ibase + row;
        const int S    = stotS[row];
        finj[hw][l32] = grow;                    // default: self -> inert slot

        const unsigned* drow = dense + row * DPAD;
        if (S <= 96) rank_core<3>(drow, S, l32, finj[hw]);
        else         rank_core<11>(drow, S, l32, finj[hw]);
        __syncthreads();

        // fp64 refine (dot + both norms) + rank-16 + laplacian
        const int j = finj[hw][l32];
        const float4* xi = (const float4*)(coords + grow * DIM);
        const float4* xj = (const float4*)(coords + j * DIM);
        double dot = 0.0, sqi = 0.0, sqj = 0.0;
        #pragma unroll
        for (int q = 0; q < DIM / 4; ++q) {
            const float4 a = xi[q], b = xj[q];
            dot += (double)a.x * (double)b.x + (double)a.y * (double)b.y
                 + (double)a.z * (double)b.z + (double)a.w * (double)b.w;
            sqi += (double)a.x * (double)a.x + (double)a.y * (double)a.y
                 + (double)a.z * (double)a.z + (double)a.w * (double)a.w;
            sqj += (double)b.x * (double)b.x + (double)b.y * (double)b.y
                 + (double)b.z * (double)b.z + (double)b.w * (double)b.w;
        }
        double d2 = sqi + sqj + 1e-5 - 2.0 * dot;
        if (j == grow) d2 = 1e300;               // self / pad slots
        refd[hw][l32] = d2;
        __syncthreads();

        int rank = 0;
        #pragma unroll 1
        for (int m = 0; m < 32; ++m) {
            const double o = refd[hw][m];
            rank += (o < d2 || (o == d2 && m < l32)) ? 1 : 0;
        }
        const double wgt = exp(-d2 * inv_den);
        double contrib = (rank < KSEL && j != grow)
                       ? wgt * ((double)pot[j] - (double)pot[grow]) : 0.0;
        #pragma unroll
        for (int off = 1; off < 32; off <<= 1)
            contrib += __shfl_xor(contrib, off, 64);
        if (l32 == 0) out[grow] = (float)contrib;
        __syncthreads();                         // finj/refd reused next pass
    }
}

extern "C" void kernel_launch(void* const* d_in, const int* in_sizes, int n_in,
                              void* d_out, int out_size, void* d_ws, size_t ws_size,
                              hipStream_t stream)
{
    (void)in_sizes; (void)n_in; (void)out_size; (void)ws_size;
    const float* coords = (const float*)d_in[0];
    const float* pot    = (const float*)d_in[1];
    // d_in[2] is k (always 16, compiled in as KSEL)

    char* w = (char*)d_ws;
    float* s1 = (float*)w;                                   // [1]
    float* sx = (float*)(w + 4);                             // [DIM]
    int*   bar = (int*)(w + 512);                            // [1]
    __hip_bfloat16* chi  = (__hip_bfloat16*)(w + 1024);      // [N*64] 1.57 MB
    __hip_bfloat16* chiX = (__hip_bfloat16*)(w + 1024 + (size_t)N_PTS * DIM * 2);
                                                             // [N*8]  196.6 KB

    hipMemsetAsync((void*)w, 0, 1024, stream);               // s1+sx+bar
    mega_kernel<<<dim3(N_PTS / 48), dim3(512), 0, stream>>>(
        coords, pot, s1, sx, bar, chi, chiX, (float*)d_out);
}